// Round 9
// baseline (245.948 us; speedup 1.0000x reference)
//
#include <hip/hip_runtime.h>

// B=8, C=128, H=128, W=256, disp in [-4,4]
// R1-verified compute/staging; dy-pair-in-grid for 4 barrier domains/CU.
#define CC   128
#define HH   128
#define WW   256
#define BB   8
#define HWS  (HH * WW)        // 32768
#define TH   16               // tile rows per block
#define TW   64               // tile cols per block
#define SROWS (TH + 8)        // 24
#define SCOLS (TW + 8)        // 72
#define STILE (SROWS * SCOLS) // 1728 floats
#define NTHR 256              // 16 rows x 16 x-chunks; one dy-PAIR per block
#define NSTG 7                // ceil(1728/256) staged positions per thread

typedef float f4 __attribute__((ext_vector_type(4)));

__global__ __launch_bounds__(NTHR, 4)   // cap 128 VGPR -> 4 blocks/CU
void corr_kernel(const float* __restrict__ first,
                 const float* __restrict__ second,
                 float* __restrict__ out)
{
    __shared__ float s_lds[2 * STILE];   // 13.8 KB double buffer

    const int tid = threadIdx.x;
    const int r   = tid >> 4;          // local row 0..15
    const int x0  = (tid & 15) << 2;   // local col of pixel 0

    // XCD swizzle: 1280 blocks = 8 images x 160; image k -> XCD k
    const int u    = (blockIdx.x & 7) * 160 + (blockIdx.x >> 3);
    const int b    = u / 160;
    const int rem  = u - b * 160;
    const int tile = rem / 5;          // 0..31
    const int m    = rem - tile * 5;   // dy-pair index 0..4
    const int xt   = tile & 3;
    const int yt   = tile >> 2;

    const int d0 = 2 * m;              // dyi of first dy (0,2,4,6,8)
    const int d1 = 2 * m + 1;          // second dy (1..9; 9 = dummy)

    const int bx = xt * TW;
    const int by = yt * TH;
    const int y  = by + r;
    const int xg = bx + x0;

    // ---- staging map (R1 pattern, 7 predicated positions)
    int  go[NSTG];
    bool vv[NSTG];
    #pragma unroll
    for (int k = 0; k < NSTG; ++k) {
        const int i  = tid + k * NTHR;
        const bool ok = (i < STILE);
        const int sr = i / SCOLS, sc = i - (i / SCOLS) * SCOLS;
        const int ys = by - 4 + sr, xs = bx - 4 + sc;
        const bool v = ok && ((unsigned)ys < HH) && ((unsigned)xs < WW);
        vv[k] = v;
        go[k] = v ? (ys * WW + xs) : 0;
    }

    const float* sbase = second + (long)b * CC * HWS;

    float acc[2][9][4];
    #pragma unroll
    for (int a = 0; a < 2; ++a)
        #pragma unroll
        for (int d = 0; d < 9; ++d)
            #pragma unroll
            for (int q = 0; q < 4; ++q)
                acc[a][d][q] = 0.0f;

    // ---- prologue: stage channel 0 into buf0
    #pragma unroll
    for (int k = 0; k < NSTG; ++k) {
        const int i = tid + k * NTHR;
        if (i < STILE) s_lds[i] = vv[k] ? sbase[go[k]] : 0.0f;
    }
    __syncthreads();

    const float* fptr = first + ((long)(b * CC) * HH + y) * WW + xg;

    // window rows (uniform per block); d1==9 clamped (dummy, store masked)
    const int srow0 = r + d0;
    const int srow1 = (d1 < 9) ? (r + d1) : 23;

    int cur = 0;
    for (int it = 0; it < CC; ++it) {
        // stage loads for channel it+1 (issued top, written bottom — R1 timing)
        const int ip = (it + 1 < CC) ? (it + 1) : it;
        const float* sb = sbase + (long)ip * HWS;
        float t[NSTG];
        #pragma unroll
        for (int k = 0; k < NSTG; ++k)
            t[k] = vv[k] ? sb[go[k]] : 0.0f;

        // first: consumed this iteration (R1-verified pattern)
        f4 fv = *(const f4*)fptr;
        fptr += HWS;

        const float* sb_lds = &s_lds[cur * STILE];
        #pragma unroll
        for (int dd = 0; dd < 2; ++dd) {
            const int srow = dd ? srow1 : srow0;
            const f4* wp = (const f4*)&sb_lds[srow * SCOLS + x0];
            f4 wa = wp[0];
            f4 wb = wp[1];
            f4 wc = wp[2];
            float w[12] = { wa[0], wa[1], wa[2], wa[3],
                            wb[0], wb[1], wb[2], wb[3],
                            wc[0], wc[1], wc[2], wc[3] };
            #pragma unroll
            for (int dxi = 0; dxi < 9; ++dxi) {
                #pragma unroll
                for (int px = 0; px < 4; ++px) {
                    acc[dd][dxi][px] = fmaf(fv[px], w[dxi + px], acc[dd][dxi][px]);
                }
            }
        }

        // write channel it+1 into other buffer, single barrier
        if (it + 1 < CC) {
            const int nb = (cur ^ 1) * STILE;
            #pragma unroll
            for (int k = 0; k < NSTG; ++k) {
                const int i = tid + k * NTHR;
                if (i < STILE) s_lds[nb + i] = t[k];
            }
        }
        __syncthreads();
        cur ^= 1;
    }

    // ---- epilogue: scale by 1/C; store dy d0 always, d1 if real
    const float scale = 1.0f / (float)CC;
    #pragma unroll
    for (int dd = 0; dd < 2; ++dd) {
        const int dyi = dd ? d1 : d0;
        if (dyi < 9) {
            #pragma unroll
            for (int dxi = 0; dxi < 9; ++dxi) {
                f4 o;
                o[0] = acc[dd][dxi][0] * scale;
                o[1] = acc[dd][dxi][1] * scale;
                o[2] = acc[dd][dxi][2] * scale;
                o[3] = acc[dd][dxi][3] * scale;
                *(f4*)(out + (long)(b * 81 + dyi * 9 + dxi) * HWS
                           + (long)y * WW + xg) = o;
            }
        }
    }
}

extern "C" void kernel_launch(void* const* d_in, const int* in_sizes, int n_in,
                              void* d_out, int out_size, void* d_ws, size_t ws_size,
                              hipStream_t stream) {
    const float* first  = (const float*)d_in[0];
    const float* second = (const float*)d_in[1];
    float* out = (float*)d_out;

    corr_kernel<<<dim3(1280), dim3(NTHR), 0, stream>>>(first, second, out);
}